// Round 24
// baseline (63.887 us; speedup 1.0000x reference)
//
#include <hip/hip_runtime.h>
#include <math.h>

// SSIM (16,3,512,512) fp32, 11x11 separable Gaussian, VALID -> per-batch mean [16].
//
// Round-24: round-16 (best: 59.4us) with the V-pass TRANSPOSED into a
// scatter-accumulate. R16's ring entries are written once and read 11 rows
// later -- the cold-value pattern the allocator parks in AGPRs (~96
// v_accvgpr moves/row = the measured 280 vs ~180 instr gap). Here each row's
// H-sums are immediately scattered into 11 pending output accumulators
// (same pkfma count), making every persistent register a hot RMW value
// touched every row. i=0 tap = pk_mul overwrite-init (no zeroing, no ring,
// no epilogue): output o=klin-10 finalizes right after the scatter.
//  - Each wave owns a 128-output-col strip (2 cols/thread) and stages its own
//    rows via global_load_lds; per-wave vmcnt(24) is the only synchronization.
//  - Channel-interleaved LDS float4(r,d,r,d); packed fp32 math (v_pk_fma_f32
//    via __builtin_elementwise_fma), {mu_r,mu_d}/{E_rr+dd,E_rd} as f32x2.
//  - 255x scaling cancels: C1 = 1e-4, C2 = 9e-4 on [0,1] data.

#define WSZ 11
#define IMG 512
#define OSZ 502
#define NT  256
#define CH_OUT 32
#define NCHUNK 16        // 16*32 >= 502
#define NSLOT 11
#define LA 6             // lookahead rows

struct WinArg { float w[WSZ]; };

typedef float f2 __attribute__((ext_vector_type(2)));
typedef float f4v __attribute__((ext_vector_type(4)));

typedef const __attribute__((address_space(1))) unsigned int* gp_t;
typedef __attribute__((address_space(3))) unsigned int* sp_t;

#define C1V 1.0e-4f
#define C2V 9.0e-4f

__device__ __forceinline__ void pkfma(f2& acc, f2 a, f2 b) {
    acc = __builtin_elementwise_fma(a, b, acc);   // v_pk_fma_f32
}

__global__ __launch_bounds__(NT, 3) void ssim_scat(
    const float* __restrict__ rawp, const float* __restrict__ dstp,
    float* __restrict__ out, WinArg wa, float inv_n)
{
    // waves 0-2: 11 slots x 80 float4 (880 f4 each); wave 3: 11 x 64 (704 f4)
    __shared__ f4v srow[3344];               // 53504 B
    __shared__ float wred[NT / 64];

    const int tid  = threadIdx.x;
    const int lane = tid & 63;
    const int wave = tid >> 6;
    const int chunk = blockIdx.x;
    const int img   = blockIdx.y;

    const int o0    = chunk * CH_OUT;
    const int olim  = min(o0 + CH_OUT, OSZ);
    const int rlast = min(o0 + CH_OUT + WSZ - 2, IMG - 1);
    const int NR    = rlast - o0 + 1;        // 42 (32 for last chunk)

    const bool w3     = (wave == 3);
    const int  nch    = w3 ? 4 : 5;          // DMA chunks per row (wave-uniform)
    const int  slotf4 = w3 ? 64 : 80;        // float4 per slot (wave-uniform)
    f4v* region = srow + wave * 880;         // wave 3 -> 2640, uses 704 f4
    const int  rl     = (w3 && lane > 58) ? 58 : lane;   // read clamp
    const bool active = !(w3 && lane > 58);

    const size_t ibase = (size_t)img * (size_t)(IMG * IMG);
    // lane parity -> channel; (lane>>1) -> col within 32-col chunk
    const float* lane_base = ((lane & 1) ? dstp : rawp) + ibase
                           + (size_t)(wave * 128 + (lane >> 1));

    // packed weights
    f2 wv[WSZ];
#pragma unroll
    for (int j = 0; j < WSZ; ++j) { wv[j].x = wa.w[j]; wv[j].y = wa.w[j]; }

#define STAGE(ROW, SLOT)                                                       \
    {                                                                          \
        const float* _s = lane_base + (size_t)(ROW) * IMG;                     \
        float* _d = (float*)(region + (SLOT) * slotf4);                        \
        _Pragma("unroll")                                                      \
        for (int _c = 0; _c < 5; ++_c) {                                       \
            if (_c < nch)                                                      \
                __builtin_amdgcn_global_load_lds(                              \
                    (gp_t)(const void*)(_s + 32 * _c),                         \
                    (sp_t)(void*)(_d + 64 * _c), 4, 0, 0);                     \
        }                                                                      \
    }

    // pending-output accumulators: slot j holds output o with o % 11 == j
    f2 m12[WSZ][2];                          // [slot][col] {mu_r, mu_d}
    f2 m34[WSZ][2];                          // [slot][col] {E_rr+dd, E_rd}
    float acc = 0.0f;

    // prologue: rows 0..LA-1 in flight (slots 0..5)
#pragma unroll
    for (int r = 0; r < LA; ++r) STAGE(o0 + r, r)

#pragma unroll 1
    for (int rr = 0; rr < NR; rr += WSZ) {
#pragma unroll
        for (int k = 0; k < WSZ; ++k) {
            const int klin = rr + k;
            if (klin < NR) {                 // block-uniform
                // stage row klin+LA (clamped tail restage lands in dead slot)
                {
                    int rs = klin + LA; if (rs > NR - 1) rs = NR - 1;
                    STAGE(o0 + rs, (k + LA) % NSLOT)
                }
                // per-wave wait: guarantees row klin's loads complete
                asm volatile("s_waitcnt vmcnt(24)" ::: "memory");

                f4v q[6];
                {
                    const f4v* rp = region + k * slotf4 + rl;
#pragma unroll
                    for (int j = 0; j < 6; ++j) q[j] = rp[j];
                }

                // ---- H-pass, 2 cols, packed channels ----
                f2 s12a = {0.f, 0.f}, s34a = {0.f, 0.f};
                f2 s12b = {0.f, 0.f}, s34b = {0.f, 0.f};
#pragma unroll
                for (int e = 0; e < 12; ++e) {
                    const f2 rd = (e & 1) ? q[e >> 1].zw : q[e >> 1].xy;
                    const f2 rr2 = rd * rd;                // v_pk_mul_f32
                    f2 sp;                                 // (r^2+d^2, r*d)
                    sp.x = rr2.x + rr2.y;
                    sp.y = rd.x * rd.y;
                    if (e < 11) {            // col a tap e
                        pkfma(s12a, wv[e], rd);
                        pkfma(s34a, wv[e], sp);
                    }
                    if (e >= 1) {            // col b tap e-1
                        pkfma(s12b, wv[e - 1], rd);
                        pkfma(s34b, wv[e - 1], sp);
                    }
                }

                // ---- scatter row klin into 11 pending outputs ----
                // output o = klin - i gets weight w[i]; slot j = (k-i) mod 11.
                // i == 0 (o = klin, newest) OVERWRITE-initializes its slot.
#pragma unroll
                for (int i = 0; i < WSZ; ++i) {
                    const int j = (k - i + WSZ) % WSZ;     // static after unroll
                    if (i == 0) {
                        m12[j][0] = wv[0] * s12a;          // v_pk_mul (init)
                        m34[j][0] = wv[0] * s34a;
                        m12[j][1] = wv[0] * s12b;
                        m34[j][1] = wv[0] * s34b;
                    } else {
                        pkfma(m12[j][0], wv[i], s12a);
                        pkfma(m34[j][0], wv[i], s34a);
                        pkfma(m12[j][1], wv[i], s12b);
                        pkfma(m34[j][1], wv[i], s34b);
                    }
                }

                // ---- finalize output o = klin-10 (slot (k+1)%11 complete) ----
                const int o = o0 + klin - (WSZ - 1);
                if (klin >= WSZ - 1 && o < olim && active) {
                    const int jf = (k + 1) % WSZ;          // static
                    {
                        const float m1 = m12[jf][0].x, m2 = m12[jf][0].y;
                        const float m3 = m34[jf][0].x, m4 = m34[jf][0].y;
                        const float q1 = m1 * m1, q2 = m2 * m2, mm = m1 * m2;
                        const float num = (2.f * mm + C1V) * (2.f * (m4 - mm) + C2V);
                        const float den = (q1 + q2 + C1V) * (((m3 - q1) - q2) + C2V);
                        acc += num * __builtin_amdgcn_rcpf(den);
                    }
                    {
                        const float m1 = m12[jf][1].x, m2 = m12[jf][1].y;
                        const float m3 = m34[jf][1].x, m4 = m34[jf][1].y;
                        const float q1 = m1 * m1, q2 = m2 * m2, mm = m1 * m2;
                        const float num = (2.f * mm + C1V) * (2.f * (m4 - mm) + C2V);
                        const float den = (q1 + q2 + C1V) * (((m3 - q1) - q2) + C2V);
                        acc += num * __builtin_amdgcn_rcpf(den);
                    }
                }
            }
        }
    }
#undef STAGE

    // ---- block reduction -> one atomicAdd per block ----
#pragma unroll
    for (int off = 32; off > 0; off >>= 1) acc += __shfl_down(acc, off, 64);
    if (lane == 0) wred[wave] = acc;
    __syncthreads();
    if (tid == 0) {
        const float tot = (wred[0] + wred[1]) + (wred[2] + wred[3]);
        atomicAdd(out + img / 3, tot * inv_n);
    }
}

extern "C" void kernel_launch(void* const* d_in, const int* in_sizes, int n_in,
                              void* d_out, int out_size, void* d_ws, size_t ws_size,
                              hipStream_t stream) {
    const float* raw = (const float*)d_in[0];
    const float* dst = (const float*)d_in[1];
    float* out = (float*)d_out;

    hipMemsetAsync(out, 0, (size_t)out_size * sizeof(float), stream);

    WinArg wa;
    double g[WSZ], s = 0.0;
    for (int i = 0; i < WSZ; ++i) {
        double ax = (double)i - (double)(WSZ - 1) / 2.0;
        g[i] = exp(-(ax * ax) / (2.0 * 1.5 * 1.5));
        s += g[i];
    }
    for (int i = 0; i < WSZ; ++i) wa.w[i] = (float)(g[i] / s);

    const float inv_n = (float)(1.0 / (3.0 * (double)OSZ * (double)OSZ));

    dim3 grid(NCHUNK, 48);
    ssim_scat<<<grid, NT, 0, stream>>>(raw, dst, out, wa, inv_n);
}